// Round 1
// baseline (1056.594 us; speedup 1.0000x reference)
//
#include <hip/hip_runtime.h>
#include <stdint.h>

// RNG_MODE: 1 = partitionable threefry (modern JAX default, bits = o0^o1, foldlike split)
//           0 = original threefry (counts split in halves)
//           2 = partitionable, bits = o1 (lo word)
//           3 = partitionable, bits = o0 (hi word)
#define RNG_MODE 1

#define Bn 4
#define An 3
#define Hn 168
#define Wn 256
#define Mn 32
#define HWn (Hn*Wn)
#define Nn (HWn*An)          // 129024  (divisible by 256 -> no tail handling)
#define HALFN (Nn/2)
#define POS_CAP 8192
#define BND_CAP 2048
#define NPERIM 256
#define NPOSMAX 128
#define FG_THR 0.7f
#define BG_THR 0.3f
#define BETA (1.0f/9.0f)

// ---- workspace layout (uint32 word offsets) ----
#define OFF_KEYS   0            // Bn*2 (written by one thread in k0, outside zero range)
#define OFF_COLMAX 8            // Bn*Mn = 128 (float bits, atomicMax)
#define OFF_POSCNT 136          // Bn
#define OFF_BNDCNT 140          // Bn
#define OFF_BOUND  144          // Bn (int32, -1 = all negatives selected)
#define OFF_NEED   148          // Bn
#define OFF_COUNT  152          // 1 (uint)
#define OFF_CLS    153          // 1 (float bits)
#define OFF_REG    154          // 1 (float bits)
#define OFF_HIST   160          // Bn*1024 = 4096 -> end 4256
#define ZERO_BEG   8
#define ZERO_END   4256
#define OFF_CAT    4256         // Bn*Nn              -> 520352
#define OFF_M      520352       // Bn*Nn              -> 1036448
#define OFF_PLIST  1036448      // Bn*POS_CAP*2       -> 1101984
#define OFF_BLIST  1101984      // Bn*BND_CAP*2       -> 1118368
// total ~4.47 MB

// ------------------- threefry2x32 (20 rounds) -------------------
__device__ __forceinline__ uint32_t rotl32(uint32_t v, int n) { return (v << n) | (v >> (32 - n)); }

__device__ __forceinline__ void tf2x32(uint32_t k0, uint32_t k1, uint32_t x0, uint32_t x1,
                                       uint32_t& o0, uint32_t& o1) {
    uint32_t k2 = k0 ^ k1 ^ 0x1BD11BDAu;
    x0 += k0; x1 += k1;
    x0 += x1; x1 = rotl32(x1, 13); x1 ^= x0;
    x0 += x1; x1 = rotl32(x1, 15); x1 ^= x0;
    x0 += x1; x1 = rotl32(x1, 26); x1 ^= x0;
    x0 += x1; x1 = rotl32(x1, 6);  x1 ^= x0;
    x0 += k1; x1 += k2 + 1u;
    x0 += x1; x1 = rotl32(x1, 17); x1 ^= x0;
    x0 += x1; x1 = rotl32(x1, 29); x1 ^= x0;
    x0 += x1; x1 = rotl32(x1, 16); x1 ^= x0;
    x0 += x1; x1 = rotl32(x1, 24); x1 ^= x0;
    x0 += k2; x1 += k0 + 2u;
    x0 += x1; x1 = rotl32(x1, 13); x1 ^= x0;
    x0 += x1; x1 = rotl32(x1, 15); x1 ^= x0;
    x0 += x1; x1 = rotl32(x1, 26); x1 ^= x0;
    x0 += x1; x1 = rotl32(x1, 6);  x1 ^= x0;
    x0 += k0; x1 += k1 + 3u;
    x0 += x1; x1 = rotl32(x1, 17); x1 ^= x0;
    x0 += x1; x1 = rotl32(x1, 29); x1 ^= x0;
    x0 += x1; x1 = rotl32(x1, 16); x1 ^= x0;
    x0 += x1; x1 = rotl32(x1, 24); x1 ^= x0;
    x0 += k1; x1 += k2 + 4u;
    x0 += x1; x1 = rotl32(x1, 13); x1 ^= x0;
    x0 += x1; x1 = rotl32(x1, 15); x1 ^= x0;
    x0 += x1; x1 = rotl32(x1, 26); x1 ^= x0;
    x0 += x1; x1 = rotl32(x1, 6);  x1 ^= x0;
    x0 += k2; x1 += k0 + 5u;
    o0 = x0; o1 = x1;
}

// 23-bit uniform integer (== mantissa of jax.random.uniform; monotone in r)
__device__ __forceinline__ uint32_t rng_m23(uint32_t k0, uint32_t k1, uint32_t i) {
    uint32_t o0, o1;
#if RNG_MODE == 0
    if (i < (uint32_t)HALFN) { tf2x32(k0, k1, i, i + HALFN, o0, o1); return o0 >> 9; }
    tf2x32(k0, k1, i - HALFN, i, o0, o1); return o1 >> 9;
#elif RNG_MODE == 1
    tf2x32(k0, k1, 0u, i, o0, o1); return (o0 ^ o1) >> 9;
#elif RNG_MODE == 2
    tf2x32(k0, k1, 0u, i, o0, o1); return o1 >> 9;
#else
    tf2x32(k0, k1, 0u, i, o0, o1); return o0 >> 9;
#endif
}

// ------------------- IoU (must match JAX op order; shared by k1/k2) -------------------
__device__ __forceinline__ float iou_one(float a0, float a1, float a2, float a3,
                                         float t0, float t1, float t2, float t3) {
    float xtl = fmaxf(a0, t0), ytl = fmaxf(a1, t1);
    float xrb = fminf(a2, t2), yrb = fminf(a3, t3);
    float iw = fmaxf(xrb - xtl + 1.0f, 0.0f);
    float ih = fmaxf(yrb - ytl + 1.0f, 0.0f);
    float inter = iw * ih;
    float area1 = (a2 - a0 + 1.0f) * (a3 - a1 + 1.0f);
    float area2 = (t2 - t0 + 1.0f) * (t3 - t1 + 1.0f);
    return inter / (area1 + area2 - inter);
}

// ------------------- K0: zero control region, derive per-image keys -------------------
__global__ void k0_init(uint32_t* __restrict__ ws) {
    int t = blockIdx.x * blockDim.x + threadIdx.x;
    for (int j = ZERO_BEG + t; j < ZERO_END; j += gridDim.x * blockDim.x) ws[j] = 0u;
    if (t == 0) {
#if RNG_MODE == 0
        uint32_t out[8];
        for (int j = 0; j < 4; ++j) {
            uint32_t o0, o1;
            tf2x32(0u, 42u, (uint32_t)j, (uint32_t)(j + 4), o0, o1);
            out[j] = o0; out[j + 4] = o1;
        }
        for (int b = 0; b < Bn; ++b) { ws[OFF_KEYS + 2*b] = out[2*b]; ws[OFF_KEYS + 2*b + 1] = out[2*b + 1]; }
#else
        for (int b = 0; b < Bn; ++b) {
            uint32_t o0, o1;
            tf2x32(0u, 42u, 0u, (uint32_t)b, o0, o1);
            ws[OFF_KEYS + 2*b] = o0; ws[OFF_KEYS + 2*b + 1] = o1;
        }
#endif
    }
}

// ------------------- K1: per-target column max IoU -------------------
__global__ void __launch_bounds__(256) k1_colmax(const float* __restrict__ anchors,
                                                 const float* __restrict__ targets,
                                                 uint32_t* __restrict__ ws) {
    int b = blockIdx.y;
    int i = blockIdx.x * 256 + threadIdx.x;
    __shared__ float tg[Mn * 4];
    if (threadIdx.x < Mn * 4) tg[threadIdx.x] = targets[b * Mn * 4 + threadIdx.x];
    __syncthreads();
    float4 av = ((const float4*)anchors)[b * Nn + i];
    int lane = threadIdx.x & 63;
    for (int t = 0; t < Mn; ++t) {
        float iou = iou_one(av.x, av.y, av.z, av.w, tg[t*4], tg[t*4+1], tg[t*4+2], tg[t*4+3]);
        for (int o = 32; o > 0; o >>= 1) iou = fmaxf(iou, __shfl_xor(iou, o, 64));
        if (lane == 0) atomicMax(&ws[OFF_COLMAX + b * Mn + t], __float_as_uint(iou));
    }
}

// ------------------- K2: categorize, RNG, histogram, positive list -------------------
__global__ void __launch_bounds__(256) k2_cat(const float* __restrict__ anchors,
                                              const float* __restrict__ targets,
                                              const float* __restrict__ sizes,
                                              uint32_t* __restrict__ ws) {
    int b = blockIdx.y;
    int i = blockIdx.x * 256 + threadIdx.x;
    __shared__ float tg[Mn * 4];
    __shared__ float cmf[Mn];
    if (threadIdx.x < Mn * 4) tg[threadIdx.x] = targets[b * Mn * 4 + threadIdx.x];
    if (threadIdx.x < Mn) cmf[threadIdx.x] = __uint_as_float(ws[OFF_COLMAX + b * Mn + threadIdx.x]);
    __syncthreads();
    float4 av = ((const float4*)anchors)[b * Nn + i];
    float rowmax = -1.0f; int ori = 0; bool restore = false;
    for (int t = 0; t < Mn; ++t) {
        float iou = iou_one(av.x, av.y, av.z, av.w, tg[t*4], tg[t*4+1], tg[t*4+2], tg[t*4+3]);
        if (iou > rowmax) { rowmax = iou; ori = t; }
        restore = restore || (iou == cmf[t]);
    }
    float sh = sizes[b * 2 + 0], sw = sizes[b * 2 + 1];
    bool inside = (av.x >= 0.0f) && (av.y >= 0.0f) && (av.z <= sw - 1.0f) && (av.w <= sh - 1.0f);
    int cat = 0;  // 0 ignore, 1 neg, 2 pos
    if (inside) {
        if (restore || rowmax >= FG_THR) cat = 2;
        else if (rowmax < BG_THR) cat = 1;
    }
    uint32_t k0 = ws[OFF_KEYS + 2 * b], k1 = ws[OFF_KEYS + 2 * b + 1];
    uint32_t m = rng_m23(k0, k1, (uint32_t)i);
    ws[OFF_CAT + b * Nn + i] = (uint32_t)cat;
    ws[OFF_M + b * Nn + i] = m;
    if (cat == 2) {
        uint32_t p = atomicAdd(&ws[OFF_POSCNT + b], 1u);
        if (p < POS_CAP) {
            ws[OFF_PLIST + ((uint32_t)b * POS_CAP + p) * 2 + 0] = m;
            ws[OFF_PLIST + ((uint32_t)b * POS_CAP + p) * 2 + 1] = (uint32_t)i | ((uint32_t)ori << 17);
        }
    } else if (cat == 1) {
        atomicAdd(&ws[OFF_HIST + b * 1024 + (m >> 13)], 1u);
    }
}

// ------------------- K2.5: find boundary bucket per image -------------------
__global__ void k25_bound(uint32_t* __restrict__ ws) {
    int b = blockIdx.x;
    if (threadIdx.x != 0) return;
    uint32_t pc = ws[OFF_POSCNT + b];
    int num_pos = (pc < (uint32_t)NPOSMAX) ? (int)pc : NPOSMAX;
    int k_neg = NPERIM - num_pos;
    int cum = 0, boundary = -1, needed = 0;
    for (int bk = 1023; bk >= 0; --bk) {
        int c = (int)ws[OFF_HIST + b * 1024 + bk];
        if (cum + c >= k_neg) { boundary = bk; needed = k_neg - cum; break; }
        cum += c;
    }
    int neg_sel = (boundary >= 0) ? k_neg : cum;
    ws[OFF_BOUND + b] = (uint32_t)boundary;
    ws[OFF_NEED + b] = (uint32_t)needed;
    atomicAdd(&ws[OFF_COUNT], (uint32_t)(num_pos + neg_sel));
}

// ------------------- K3: BCE sum for clearly-selected negatives; gather boundary -------------------
__global__ void __launch_bounds__(256) k3_neg(const float* __restrict__ logits,
                                              uint32_t* __restrict__ ws) {
    int b = blockIdx.y;
    int i = blockIdx.x * 256 + threadIdx.x;
    float local = 0.0f;
    uint32_t cat = ws[OFF_CAT + b * Nn + i];
    if (cat == 1u) {
        uint32_t m = ws[OFF_M + b * Nn + i];
        int bk = (int)(m >> 13);
        int bd = (int)(int32_t)ws[OFF_BOUND + b];
        if (bk > bd) {
            int a = i % An, hw = i / An;
            float l = logits[(b * An + a) * HWn + hw];
            local = fmaxf(l, 0.0f) + log1pf(expf(-fabsf(l)));   // BCE(l, 0)
        } else if (bk == bd) {
            uint32_t p = atomicAdd(&ws[OFF_BNDCNT + b], 1u);
            if (p < BND_CAP) {
                ws[OFF_BLIST + ((uint32_t)b * BND_CAP + p) * 2 + 0] = m;
                ws[OFF_BLIST + ((uint32_t)b * BND_CAP + p) * 2 + 1] = (uint32_t)i;
            }
        }
    }
    __shared__ float red[256];
    red[threadIdx.x] = local;
    __syncthreads();
    for (int s = 128; s > 0; s >>= 1) {
        if ((int)threadIdx.x < s) red[threadIdx.x] += red[threadIdx.x + s];
        __syncthreads();
    }
    if (threadIdx.x == 0 && red[0] != 0.0f) atomicAdd((float*)&ws[OFF_CLS], red[0]);
}

// ------------------- K4: per-image finalize (sort boundary, positives, reg loss) -------------------
__device__ __forceinline__ bool sel_less(uint2 a, uint2 b) {
    // selection order: larger priority m first; tie -> smaller index first (JAX top_k)
    return (a.x > b.x) || (a.x == b.x && a.y < b.y);
}

__device__ void bitonic_sort_shared(uint2* buf, int n) {   // n = pow2
    for (int k = 2; k <= n; k <<= 1) {
        for (int j = k >> 1; j > 0; j >>= 1) {
            for (int t = (int)threadIdx.x; t < n; t += 256) {
                int ixj = t ^ j;
                if (ixj > t) {
                    uint2 x = buf[t], y = buf[ixj];
                    bool up = ((t & k) == 0);
                    bool sw = up ? sel_less(y, x) : sel_less(x, y);
                    if (sw) { buf[t] = y; buf[ixj] = x; }
                }
            }
            __syncthreads();
        }
    }
}

__global__ void __launch_bounds__(256) k4_final(const float* __restrict__ anchors,
                                                const float* __restrict__ targets,
                                                const float* __restrict__ logits,
                                                const float* __restrict__ bregs,
                                                uint32_t* __restrict__ ws) {
    int b = blockIdx.x;
    __shared__ uint2 buf[BND_CAP];
    __shared__ float red[256];
    float cls = 0.0f, reg = 0.0f;

    // ----- positives -----
    uint32_t pcu = ws[OFF_POSCNT + b];
    int pc = (pcu < (uint32_t)POS_CAP) ? (int)pcu : POS_CAP;
    const uint32_t* plist = ws + OFF_PLIST + (size_t)b * POS_CAP * 2;
    int psel = (pc < NPOSMAX) ? pc : NPOSMAX;
    bool use_buf = false;
    if (pc > NPOSMAX) {
        int n = (pc < BND_CAP) ? pc : BND_CAP;
        for (int j = (int)threadIdx.x; j < n; j += 256) buf[j] = make_uint2(plist[2*j], plist[2*j+1]);
        int npad = 1; while (npad < n) npad <<= 1;
        for (int j = (int)threadIdx.x; j < npad; j += 256) if (j >= n) buf[j] = make_uint2(0u, 0xFFFFFFFFu);
        __syncthreads();
        bitonic_sort_shared(buf, npad);
        use_buf = true;
        psel = (NPOSMAX < n) ? NPOSMAX : n;
    }
    for (int j = (int)threadIdx.x; j < psel; j += 256) {
        uint32_t packed = use_buf ? buf[j].y : plist[2*j+1];
        int i = (int)(packed & 0x1FFFFu);
        int ori = (int)(packed >> 17);
        int a = i % An, hw = i / An;
        float l = logits[(b * An + a) * HWn + hw];
        cls += fmaxf(l, 0.0f) - l + log1pf(expf(-fabsf(l)));   // BCE(l, 1)
        float4 av = ((const float4*)anchors)[b * Nn + i];
        float4 tv = ((const float4*)targets)[b * Mn + ori];
        float aws = av.z - av.x + 1.0f, ahs = av.w - av.y + 1.0f;
        float axc = av.x + 0.5f * aws, ayc = av.y + 0.5f * ahs;
        float tws = tv.z - tv.x + 1.0f, ths = tv.w - tv.y + 1.0f;
        float txc = tv.x + 0.5f * tws, tyc = tv.y + 0.5f * ths;
        float off0 = (txc - axc) / aws;
        float off1 = (tyc - ayc) / ahs;
        float off2 = logf(tws / aws);
        float off3 = logf(ths / ahs);
        float br0 = bregs[(b * 12 + a * 4 + 0) * HWn + hw];
        float br1 = bregs[(b * 12 + a * 4 + 1) * HWn + hw];
        float br2 = bregs[(b * 12 + a * 4 + 2) * HWn + hw];
        float br3 = bregs[(b * 12 + a * 4 + 3) * HWn + hw];
        float d;
        d = fabsf(br0 - off0); reg += (d < BETA) ? 0.5f * d * d / BETA : d - 0.5f * BETA;
        d = fabsf(br1 - off1); reg += (d < BETA) ? 0.5f * d * d / BETA : d - 0.5f * BETA;
        d = fabsf(br2 - off2); reg += (d < BETA) ? 0.5f * d * d / BETA : d - 0.5f * BETA;
        d = fabsf(br3 - off3); reg += (d < BETA) ? 0.5f * d * d / BETA : d - 0.5f * BETA;
    }
    __syncthreads();

    // ----- boundary-bucket negatives -----
    int need = (int)ws[OFF_NEED + b];
    if (need > 0) {
        uint32_t nbu = ws[OFF_BNDCNT + b];
        int nb = (nbu < (uint32_t)BND_CAP) ? (int)nbu : BND_CAP;
        const uint32_t* blist = ws + OFF_BLIST + (size_t)b * BND_CAP * 2;
        for (int j = (int)threadIdx.x; j < nb; j += 256) buf[j] = make_uint2(blist[2*j], blist[2*j+1]);
        int npad = 1; while (npad < nb) npad <<= 1;
        for (int j = (int)threadIdx.x; j < npad; j += 256) if (j >= nb) buf[j] = make_uint2(0u, 0xFFFFFFFFu);
        __syncthreads();
        bitonic_sort_shared(buf, npad);
        int sel = (need < nb) ? need : nb;
        for (int j = (int)threadIdx.x; j < sel; j += 256) {
            int i = (int)buf[j].y;
            int a = i % An, hw = i / An;
            float l = logits[(b * An + a) * HWn + hw];
            cls += fmaxf(l, 0.0f) + log1pf(expf(-fabsf(l)));   // BCE(l, 0)
        }
    }

    // ----- block reductions -----
    red[threadIdx.x] = cls;
    __syncthreads();
    for (int s = 128; s > 0; s >>= 1) {
        if ((int)threadIdx.x < s) red[threadIdx.x] += red[threadIdx.x + s];
        __syncthreads();
    }
    if (threadIdx.x == 0 && red[0] != 0.0f) atomicAdd((float*)&ws[OFF_CLS], red[0]);
    __syncthreads();
    red[threadIdx.x] = reg;
    __syncthreads();
    for (int s = 128; s > 0; s >>= 1) {
        if ((int)threadIdx.x < s) red[threadIdx.x] += red[threadIdx.x + s];
        __syncthreads();
    }
    if (threadIdx.x == 0 && red[0] != 0.0f) atomicAdd((float*)&ws[OFF_REG], red[0]);
}

// ------------------- K5: divide -------------------
__global__ void k5_out(const uint32_t* __restrict__ ws, float* __restrict__ out) {
    if (blockIdx.x == 0 && threadIdx.x == 0) {
        float cnt = (float)ws[OFF_COUNT];
        out[0] = __uint_as_float(ws[OFF_CLS]) / cnt;
        out[1] = __uint_as_float(ws[OFF_REG]) / cnt;
    }
}

extern "C" void kernel_launch(void* const* d_in, const int* in_sizes, int n_in,
                              void* d_out, int out_size, void* d_ws, size_t ws_size,
                              hipStream_t stream) {
    const float* anchors = (const float*)d_in[0];   // [B, N, 4]
    const float* logits  = (const float*)d_in[1];   // [B, A, H, W]
    const float* bregs   = (const float*)d_in[2];   // [B, 4A, H, W]
    const float* sizes   = (const float*)d_in[3];   // [B, 2]
    const float* targets = (const float*)d_in[4];   // [B, M, 4]
    float* out = (float*)d_out;
    uint32_t* ws = (uint32_t*)d_ws;

    dim3 gridN(Nn / 256, Bn);
    k0_init<<<dim3(64), dim3(256), 0, stream>>>(ws);
    k1_colmax<<<gridN, dim3(256), 0, stream>>>(anchors, targets, ws);
    k2_cat<<<gridN, dim3(256), 0, stream>>>(anchors, targets, sizes, ws);
    k25_bound<<<dim3(Bn), dim3(64), 0, stream>>>(ws);
    k3_neg<<<gridN, dim3(256), 0, stream>>>(logits, ws);
    k4_final<<<dim3(Bn), dim3(256), 0, stream>>>(anchors, targets, logits, bregs, ws);
    k5_out<<<dim3(1), dim3(64), 0, stream>>>(ws, out);
}

// Round 2
// 186.067 us; speedup vs baseline: 5.6786x; 5.6786x over previous
//
#include <hip/hip_runtime.h>
#include <stdint.h>

// RNG_MODE: 1 = partitionable threefry (modern JAX default, bits = o0^o1, foldlike split)
#define RNG_MODE 1

#define Bn 4
#define An 3
#define Hn 168
#define Wn 256
#define Mn 32
#define HWn (Hn*Wn)
#define Nn (HWn*An)          // 129024  (divisible by 256 -> no tail handling)
#define HALFN (Nn/2)
#define POS_CAP 8192
#define BND_CAP 2048
#define NPERIM 256
#define NPOSMAX 128
#define FG_THR 0.7f
#define BG_THR 0.3f
#define BETA (1.0f/9.0f)

// ---- workspace layout (uint32 word offsets) ----
#define OFF_KEYS   0            // Bn*2 (written by one thread in k0, outside zero range)
#define OFF_COLMAX 8            // Bn*Mn = 128 (float bits, atomicMax)
#define OFF_POSCNT 136          // Bn
#define OFF_BNDCNT 140          // Bn
#define OFF_BOUND  144          // Bn (int32, -1 = all negatives selected)
#define OFF_NEED   148          // Bn
#define OFF_COUNT  152          // 1 (uint)
#define OFF_CLS    153          // 1 (float bits)
#define OFF_REG    154          // 1 (float bits)
#define OFF_HIST   160          // Bn*1024 = 4096 -> end 4256
#define ZERO_BEG   8
#define ZERO_END   4256
#define OFF_CAT    4256         // Bn*Nn              -> 520352
#define OFF_M      520352       // Bn*Nn              -> 1036448
#define OFF_PLIST  1036448      // Bn*POS_CAP*2       -> 1101984
#define OFF_BLIST  1101984      // Bn*BND_CAP*2       -> 1118368
// total ~4.47 MB

// ------------------- threefry2x32 (20 rounds) -------------------
__device__ __forceinline__ uint32_t rotl32(uint32_t v, int n) { return (v << n) | (v >> (32 - n)); }

__device__ __forceinline__ void tf2x32(uint32_t k0, uint32_t k1, uint32_t x0, uint32_t x1,
                                       uint32_t& o0, uint32_t& o1) {
    uint32_t k2 = k0 ^ k1 ^ 0x1BD11BDAu;
    x0 += k0; x1 += k1;
    x0 += x1; x1 = rotl32(x1, 13); x1 ^= x0;
    x0 += x1; x1 = rotl32(x1, 15); x1 ^= x0;
    x0 += x1; x1 = rotl32(x1, 26); x1 ^= x0;
    x0 += x1; x1 = rotl32(x1, 6);  x1 ^= x0;
    x0 += k1; x1 += k2 + 1u;
    x0 += x1; x1 = rotl32(x1, 17); x1 ^= x0;
    x0 += x1; x1 = rotl32(x1, 29); x1 ^= x0;
    x0 += x1; x1 = rotl32(x1, 16); x1 ^= x0;
    x0 += x1; x1 = rotl32(x1, 24); x1 ^= x0;
    x0 += k2; x1 += k0 + 2u;
    x0 += x1; x1 = rotl32(x1, 13); x1 ^= x0;
    x0 += x1; x1 = rotl32(x1, 15); x1 ^= x0;
    x0 += x1; x1 = rotl32(x1, 26); x1 ^= x0;
    x0 += x1; x1 = rotl32(x1, 6);  x1 ^= x0;
    x0 += k0; x1 += k1 + 3u;
    x0 += x1; x1 = rotl32(x1, 17); x1 ^= x0;
    x0 += x1; x1 = rotl32(x1, 29); x1 ^= x0;
    x0 += x1; x1 = rotl32(x1, 16); x1 ^= x0;
    x0 += x1; x1 = rotl32(x1, 24); x1 ^= x0;
    x0 += k1; x1 += k2 + 4u;
    x0 += x1; x1 = rotl32(x1, 13); x1 ^= x0;
    x0 += x1; x1 = rotl32(x1, 15); x1 ^= x0;
    x0 += x1; x1 = rotl32(x1, 26); x1 ^= x0;
    x0 += x1; x1 = rotl32(x1, 6);  x1 ^= x0;
    x0 += k2; x1 += k0 + 5u;
    o0 = x0; o1 = x1;
}

// 23-bit uniform integer (== mantissa of jax.random.uniform; monotone in r)
__device__ __forceinline__ uint32_t rng_m23(uint32_t k0, uint32_t k1, uint32_t i) {
    uint32_t o0, o1;
    tf2x32(k0, k1, 0u, i, o0, o1);
    return (o0 ^ o1) >> 9;
}

// ------------------- IoU (must match JAX op order; shared by k1/k2) -------------------
__device__ __forceinline__ float iou_one(float a0, float a1, float a2, float a3,
                                         float t0, float t1, float t2, float t3) {
    float xtl = fmaxf(a0, t0), ytl = fmaxf(a1, t1);
    float xrb = fminf(a2, t2), yrb = fminf(a3, t3);
    float iw = fmaxf(xrb - xtl + 1.0f, 0.0f);
    float ih = fmaxf(yrb - ytl + 1.0f, 0.0f);
    float inter = iw * ih;
    float area1 = (a2 - a0 + 1.0f) * (a3 - a1 + 1.0f);
    float area2 = (t2 - t0 + 1.0f) * (t3 - t1 + 1.0f);
    return inter / (area1 + area2 - inter);
}

// ------------------- K0: zero control region, derive per-image keys -------------------
__global__ void k0_init(uint32_t* __restrict__ ws) {
    int t = blockIdx.x * blockDim.x + threadIdx.x;
    for (int j = ZERO_BEG + t; j < ZERO_END; j += gridDim.x * blockDim.x) ws[j] = 0u;
    if (t == 0) {
        for (int b = 0; b < Bn; ++b) {
            uint32_t o0, o1;
            tf2x32(0u, 42u, 0u, (uint32_t)b, o0, o1);
            ws[OFF_KEYS + 2*b] = o0; ws[OFF_KEYS + 2*b + 1] = o1;
        }
    }
}

// ------------------- K1: per-target column max IoU -------------------
// Register-accumulated colmax: 64 blocks/image, cm[32] per thread, wave shuffle
// reduce -> cross-wave LDS reduce -> 32 atomics per block (8192 total vs 1.03M
// before, which serialized on 128 words and cost ~940us).
#define K1_BLOCKS 64
__global__ void __launch_bounds__(256) k1_colmax(const float* __restrict__ anchors,
                                                 const float* __restrict__ targets,
                                                 uint32_t* __restrict__ ws) {
    int b = blockIdx.y;
    __shared__ float tg[Mn * 4];
    __shared__ float part[4][Mn];
    if (threadIdx.x < Mn * 4) tg[threadIdx.x] = targets[b * Mn * 4 + threadIdx.x];
    __syncthreads();
    float cm[Mn];
    #pragma unroll
    for (int t = 0; t < Mn; ++t) cm[t] = 0.0f;
    const int stride = K1_BLOCKS * 256;
    for (int i = blockIdx.x * 256 + threadIdx.x; i < Nn; i += stride) {
        float4 av = ((const float4*)anchors)[b * Nn + i];
        #pragma unroll
        for (int t = 0; t < Mn; ++t) {
            float iou = iou_one(av.x, av.y, av.z, av.w, tg[t*4], tg[t*4+1], tg[t*4+2], tg[t*4+3]);
            cm[t] = fmaxf(cm[t], iou);
        }
    }
    #pragma unroll
    for (int t = 0; t < Mn; ++t) {
        #pragma unroll
        for (int o = 32; o > 0; o >>= 1) cm[t] = fmaxf(cm[t], __shfl_xor(cm[t], o, 64));
    }
    int wid = threadIdx.x >> 6, lane = threadIdx.x & 63;
    if (lane == 0) {
        #pragma unroll
        for (int t = 0; t < Mn; ++t) part[wid][t] = cm[t];
    }
    __syncthreads();
    if (threadIdx.x < Mn) {
        float v = fmaxf(fmaxf(part[0][threadIdx.x], part[1][threadIdx.x]),
                        fmaxf(part[2][threadIdx.x], part[3][threadIdx.x]));
        atomicMax(&ws[OFF_COLMAX + b * Mn + threadIdx.x], __float_as_uint(v));
    }
}

// ------------------- K2: categorize, RNG, histogram, positive list -------------------
__global__ void __launch_bounds__(256) k2_cat(const float* __restrict__ anchors,
                                              const float* __restrict__ targets,
                                              const float* __restrict__ sizes,
                                              uint32_t* __restrict__ ws) {
    int b = blockIdx.y;
    int i = blockIdx.x * 256 + threadIdx.x;
    __shared__ float tg[Mn * 4];
    __shared__ float cmf[Mn];
    if (threadIdx.x < Mn * 4) tg[threadIdx.x] = targets[b * Mn * 4 + threadIdx.x];
    if (threadIdx.x < Mn) cmf[threadIdx.x] = __uint_as_float(ws[OFF_COLMAX + b * Mn + threadIdx.x]);
    __syncthreads();
    float4 av = ((const float4*)anchors)[b * Nn + i];
    float rowmax = -1.0f; int ori = 0; bool restore = false;
    for (int t = 0; t < Mn; ++t) {
        float iou = iou_one(av.x, av.y, av.z, av.w, tg[t*4], tg[t*4+1], tg[t*4+2], tg[t*4+3]);
        if (iou > rowmax) { rowmax = iou; ori = t; }
        restore = restore || (iou == cmf[t]);
    }
    float sh = sizes[b * 2 + 0], sw = sizes[b * 2 + 1];
    bool inside = (av.x >= 0.0f) && (av.y >= 0.0f) && (av.z <= sw - 1.0f) && (av.w <= sh - 1.0f);
    int cat = 0;  // 0 ignore, 1 neg, 2 pos
    if (inside) {
        if (restore || rowmax >= FG_THR) cat = 2;
        else if (rowmax < BG_THR) cat = 1;
    }
    uint32_t k0 = ws[OFF_KEYS + 2 * b], k1 = ws[OFF_KEYS + 2 * b + 1];
    uint32_t m = rng_m23(k0, k1, (uint32_t)i);
    ws[OFF_CAT + b * Nn + i] = (uint32_t)cat;
    ws[OFF_M + b * Nn + i] = m;
    if (cat == 2) {
        uint32_t p = atomicAdd(&ws[OFF_POSCNT + b], 1u);
        if (p < POS_CAP) {
            ws[OFF_PLIST + ((uint32_t)b * POS_CAP + p) * 2 + 0] = m;
            ws[OFF_PLIST + ((uint32_t)b * POS_CAP + p) * 2 + 1] = (uint32_t)i | ((uint32_t)ori << 17);
        }
    } else if (cat == 1) {
        atomicAdd(&ws[OFF_HIST + b * 1024 + (m >> 13)], 1u);
    }
}

// ------------------- K2.5: find boundary bucket per image -------------------
__global__ void k25_bound(uint32_t* __restrict__ ws) {
    int b = blockIdx.x;
    if (threadIdx.x != 0) return;
    uint32_t pc = ws[OFF_POSCNT + b];
    int num_pos = (pc < (uint32_t)NPOSMAX) ? (int)pc : NPOSMAX;
    int k_neg = NPERIM - num_pos;
    int cum = 0, boundary = -1, needed = 0;
    for (int bk = 1023; bk >= 0; --bk) {
        int c = (int)ws[OFF_HIST + b * 1024 + bk];
        if (cum + c >= k_neg) { boundary = bk; needed = k_neg - cum; break; }
        cum += c;
    }
    int neg_sel = (boundary >= 0) ? k_neg : cum;
    ws[OFF_BOUND + b] = (uint32_t)boundary;
    ws[OFF_NEED + b] = (uint32_t)needed;
    atomicAdd(&ws[OFF_COUNT], (uint32_t)(num_pos + neg_sel));
}

// ------------------- K3: BCE sum for clearly-selected negatives; gather boundary -------------------
__global__ void __launch_bounds__(256) k3_neg(const float* __restrict__ logits,
                                              uint32_t* __restrict__ ws) {
    int b = blockIdx.y;
    int i = blockIdx.x * 256 + threadIdx.x;
    float local = 0.0f;
    uint32_t cat = ws[OFF_CAT + b * Nn + i];
    if (cat == 1u) {
        uint32_t m = ws[OFF_M + b * Nn + i];
        int bk = (int)(m >> 13);
        int bd = (int)(int32_t)ws[OFF_BOUND + b];
        if (bk > bd) {
            int a = i % An, hw = i / An;
            float l = logits[(b * An + a) * HWn + hw];
            local = fmaxf(l, 0.0f) + log1pf(expf(-fabsf(l)));   // BCE(l, 0)
        } else if (bk == bd) {
            uint32_t p = atomicAdd(&ws[OFF_BNDCNT + b], 1u);
            if (p < BND_CAP) {
                ws[OFF_BLIST + ((uint32_t)b * BND_CAP + p) * 2 + 0] = m;
                ws[OFF_BLIST + ((uint32_t)b * BND_CAP + p) * 2 + 1] = (uint32_t)i;
            }
        }
    }
    __shared__ float red[256];
    red[threadIdx.x] = local;
    __syncthreads();
    for (int s = 128; s > 0; s >>= 1) {
        if ((int)threadIdx.x < s) red[threadIdx.x] += red[threadIdx.x + s];
        __syncthreads();
    }
    if (threadIdx.x == 0 && red[0] != 0.0f) atomicAdd((float*)&ws[OFF_CLS], red[0]);
}

// ------------------- K4: per-image finalize (sort boundary, positives, reg loss) -------------------
__device__ __forceinline__ bool sel_less(uint2 a, uint2 b) {
    // selection order: larger priority m first; tie -> smaller index first (JAX top_k)
    return (a.x > b.x) || (a.x == b.x && a.y < b.y);
}

__device__ void bitonic_sort_shared(uint2* buf, int n) {   // n = pow2
    for (int k = 2; k <= n; k <<= 1) {
        for (int j = k >> 1; j > 0; j >>= 1) {
            for (int t = (int)threadIdx.x; t < n; t += 256) {
                int ixj = t ^ j;
                if (ixj > t) {
                    uint2 x = buf[t], y = buf[ixj];
                    bool up = ((t & k) == 0);
                    bool sw = up ? sel_less(y, x) : sel_less(x, y);
                    if (sw) { buf[t] = y; buf[ixj] = x; }
                }
            }
            __syncthreads();
        }
    }
}

__global__ void __launch_bounds__(256) k4_final(const float* __restrict__ anchors,
                                                const float* __restrict__ targets,
                                                const float* __restrict__ logits,
                                                const float* __restrict__ bregs,
                                                uint32_t* __restrict__ ws) {
    int b = blockIdx.x;
    __shared__ uint2 buf[BND_CAP];
    __shared__ float red[256];
    float cls = 0.0f, reg = 0.0f;

    // ----- positives -----
    uint32_t pcu = ws[OFF_POSCNT + b];
    int pc = (pcu < (uint32_t)POS_CAP) ? (int)pcu : POS_CAP;
    const uint32_t* plist = ws + OFF_PLIST + (size_t)b * POS_CAP * 2;
    int psel = (pc < NPOSMAX) ? pc : NPOSMAX;
    bool use_buf = false;
    if (pc > NPOSMAX) {
        int n = (pc < BND_CAP) ? pc : BND_CAP;
        for (int j = (int)threadIdx.x; j < n; j += 256) buf[j] = make_uint2(plist[2*j], plist[2*j+1]);
        int npad = 1; while (npad < n) npad <<= 1;
        for (int j = (int)threadIdx.x; j < npad; j += 256) if (j >= n) buf[j] = make_uint2(0u, 0xFFFFFFFFu);
        __syncthreads();
        bitonic_sort_shared(buf, npad);
        use_buf = true;
        psel = (NPOSMAX < n) ? NPOSMAX : n;
    }
    for (int j = (int)threadIdx.x; j < psel; j += 256) {
        uint32_t packed = use_buf ? buf[j].y : plist[2*j+1];
        int i = (int)(packed & 0x1FFFFu);
        int ori = (int)(packed >> 17);
        int a = i % An, hw = i / An;
        float l = logits[(b * An + a) * HWn + hw];
        cls += fmaxf(l, 0.0f) - l + log1pf(expf(-fabsf(l)));   // BCE(l, 1)
        float4 av = ((const float4*)anchors)[b * Nn + i];
        float4 tv = ((const float4*)targets)[b * Mn + ori];
        float aws = av.z - av.x + 1.0f, ahs = av.w - av.y + 1.0f;
        float axc = av.x + 0.5f * aws, ayc = av.y + 0.5f * ahs;
        float tws = tv.z - tv.x + 1.0f, ths = tv.w - tv.y + 1.0f;
        float txc = tv.x + 0.5f * tws, tyc = tv.y + 0.5f * ths;
        float off0 = (txc - axc) / aws;
        float off1 = (tyc - ayc) / ahs;
        float off2 = logf(tws / aws);
        float off3 = logf(ths / ahs);
        float br0 = bregs[(b * 12 + a * 4 + 0) * HWn + hw];
        float br1 = bregs[(b * 12 + a * 4 + 1) * HWn + hw];
        float br2 = bregs[(b * 12 + a * 4 + 2) * HWn + hw];
        float br3 = bregs[(b * 12 + a * 4 + 3) * HWn + hw];
        float d;
        d = fabsf(br0 - off0); reg += (d < BETA) ? 0.5f * d * d / BETA : d - 0.5f * BETA;
        d = fabsf(br1 - off1); reg += (d < BETA) ? 0.5f * d * d / BETA : d - 0.5f * BETA;
        d = fabsf(br2 - off2); reg += (d < BETA) ? 0.5f * d * d / BETA : d - 0.5f * BETA;
        d = fabsf(br3 - off3); reg += (d < BETA) ? 0.5f * d * d / BETA : d - 0.5f * BETA;
    }
    __syncthreads();

    // ----- boundary-bucket negatives -----
    int need = (int)ws[OFF_NEED + b];
    if (need > 0) {
        uint32_t nbu = ws[OFF_BNDCNT + b];
        int nb = (nbu < (uint32_t)BND_CAP) ? (int)nbu : BND_CAP;
        const uint32_t* blist = ws + OFF_BLIST + (size_t)b * BND_CAP * 2;
        for (int j = (int)threadIdx.x; j < nb; j += 256) buf[j] = make_uint2(blist[2*j], blist[2*j+1]);
        int npad = 1; while (npad < nb) npad <<= 1;
        for (int j = (int)threadIdx.x; j < npad; j += 256) if (j >= nb) buf[j] = make_uint2(0u, 0xFFFFFFFFu);
        __syncthreads();
        bitonic_sort_shared(buf, npad);
        int sel = (need < nb) ? need : nb;
        for (int j = (int)threadIdx.x; j < sel; j += 256) {
            int i = (int)buf[j].y;
            int a = i % An, hw = i / An;
            float l = logits[(b * An + a) * HWn + hw];
            cls += fmaxf(l, 0.0f) + log1pf(expf(-fabsf(l)));   // BCE(l, 0)
        }
    }

    // ----- block reductions -----
    red[threadIdx.x] = cls;
    __syncthreads();
    for (int s = 128; s > 0; s >>= 1) {
        if ((int)threadIdx.x < s) red[threadIdx.x] += red[threadIdx.x + s];
        __syncthreads();
    }
    if (threadIdx.x == 0 && red[0] != 0.0f) atomicAdd((float*)&ws[OFF_CLS], red[0]);
    __syncthreads();
    red[threadIdx.x] = reg;
    __syncthreads();
    for (int s = 128; s > 0; s >>= 1) {
        if ((int)threadIdx.x < s) red[threadIdx.x] += red[threadIdx.x + s];
        __syncthreads();
    }
    if (threadIdx.x == 0 && red[0] != 0.0f) atomicAdd((float*)&ws[OFF_REG], red[0]);
}

// ------------------- K5: divide -------------------
__global__ void k5_out(const uint32_t* __restrict__ ws, float* __restrict__ out) {
    if (blockIdx.x == 0 && threadIdx.x == 0) {
        float cnt = (float)ws[OFF_COUNT];
        out[0] = __uint_as_float(ws[OFF_CLS]) / cnt;
        out[1] = __uint_as_float(ws[OFF_REG]) / cnt;
    }
}

extern "C" void kernel_launch(void* const* d_in, const int* in_sizes, int n_in,
                              void* d_out, int out_size, void* d_ws, size_t ws_size,
                              hipStream_t stream) {
    const float* anchors = (const float*)d_in[0];   // [B, N, 4]
    const float* logits  = (const float*)d_in[1];   // [B, A, H, W]
    const float* bregs   = (const float*)d_in[2];   // [B, 4A, H, W]
    const float* sizes   = (const float*)d_in[3];   // [B, 2]
    const float* targets = (const float*)d_in[4];   // [B, M, 4]
    float* out = (float*)d_out;
    uint32_t* ws = (uint32_t*)d_ws;

    dim3 gridN(Nn / 256, Bn);
    k0_init<<<dim3(64), dim3(256), 0, stream>>>(ws);
    k1_colmax<<<dim3(K1_BLOCKS, Bn), dim3(256), 0, stream>>>(anchors, targets, ws);
    k2_cat<<<gridN, dim3(256), 0, stream>>>(anchors, targets, sizes, ws);
    k25_bound<<<dim3(Bn), dim3(64), 0, stream>>>(ws);
    k3_neg<<<gridN, dim3(256), 0, stream>>>(logits, ws);
    k4_final<<<dim3(Bn), dim3(256), 0, stream>>>(anchors, targets, logits, bregs, ws);
    k5_out<<<dim3(1), dim3(64), 0, stream>>>(ws, out);
}

// Round 3
// 177.742 us; speedup vs baseline: 5.9445x; 1.0468x over previous
//
#include <hip/hip_runtime.h>
#include <stdint.h>

#define Bn 4
#define An 3
#define Hn 168
#define Wn 256
#define Mn 32
#define HWn (Hn*Wn)
#define Nn (HWn*An)          // 129024  (divisible by 256 -> no tail handling)
#define POS_CAP 8192
#define BND_CAP 2048
#define NPERIM 256
#define NPOSMAX 128
#define FG_THR 0.7f
#define BG_THR 0.3f
#define BETA (1.0f/9.0f)

// ---- workspace layout (uint32 word offsets) ----
#define OFF_KEYS   0            // Bn*2 (written in k0, outside zero range)
#define OFF_COLMAX 8            // Bn*Mn = 128 (float bits, atomicMax)
#define OFF_POSCNT 136          // Bn
#define OFF_BNDCNT 140          // Bn
#define OFF_BOUND  144          // Bn (int32, -1 = all negatives selected)
#define OFF_NEED   148          // Bn
#define OFF_COUNT  152          // 1 (uint)
#define OFF_CLS    153          // 1 (float bits)
#define OFF_REG    154          // 1 (float bits)
#define OFF_DONE   155          // 1 (uint, k4 completion counter)
#define OFF_HIST   160          // Bn*1024 = 4096 -> end 4256
#define ZERO_BEG   8
#define ZERO_END   4256
#define OFF_PACK   4256         // Bn*Nn  (m | cat<<24)   -> 520352
#define OFF_PLIST  520352       // Bn*POS_CAP*2           -> 585888
#define OFF_BLIST  585888       // Bn*BND_CAP*2           -> 602272

// ------------------- threefry2x32 (20 rounds) -------------------
__device__ __forceinline__ uint32_t rotl32(uint32_t v, int n) { return (v << n) | (v >> (32 - n)); }

__device__ __forceinline__ void tf2x32(uint32_t k0, uint32_t k1, uint32_t x0, uint32_t x1,
                                       uint32_t& o0, uint32_t& o1) {
    uint32_t k2 = k0 ^ k1 ^ 0x1BD11BDAu;
    x0 += k0; x1 += k1;
    x0 += x1; x1 = rotl32(x1, 13); x1 ^= x0;
    x0 += x1; x1 = rotl32(x1, 15); x1 ^= x0;
    x0 += x1; x1 = rotl32(x1, 26); x1 ^= x0;
    x0 += x1; x1 = rotl32(x1, 6);  x1 ^= x0;
    x0 += k1; x1 += k2 + 1u;
    x0 += x1; x1 = rotl32(x1, 17); x1 ^= x0;
    x0 += x1; x1 = rotl32(x1, 29); x1 ^= x0;
    x0 += x1; x1 = rotl32(x1, 16); x1 ^= x0;
    x0 += x1; x1 = rotl32(x1, 24); x1 ^= x0;
    x0 += k2; x1 += k0 + 2u;
    x0 += x1; x1 = rotl32(x1, 13); x1 ^= x0;
    x0 += x1; x1 = rotl32(x1, 15); x1 ^= x0;
    x0 += x1; x1 = rotl32(x1, 26); x1 ^= x0;
    x0 += x1; x1 = rotl32(x1, 6);  x1 ^= x0;
    x0 += k0; x1 += k1 + 3u;
    x0 += x1; x1 = rotl32(x1, 17); x1 ^= x0;
    x0 += x1; x1 = rotl32(x1, 29); x1 ^= x0;
    x0 += x1; x1 = rotl32(x1, 16); x1 ^= x0;
    x0 += x1; x1 = rotl32(x1, 24); x1 ^= x0;
    x0 += k1; x1 += k2 + 4u;
    x0 += x1; x1 = rotl32(x1, 13); x1 ^= x0;
    x0 += x1; x1 = rotl32(x1, 15); x1 ^= x0;
    x0 += x1; x1 = rotl32(x1, 26); x1 ^= x0;
    x0 += x1; x1 = rotl32(x1, 6);  x1 ^= x0;
    x0 += k2; x1 += k0 + 5u;
    o0 = x0; o1 = x1;
}

__device__ __forceinline__ uint32_t rng_m23(uint32_t k0, uint32_t k1, uint32_t i) {
    uint32_t o0, o1;
    tf2x32(k0, k1, 0u, i, o0, o1);
    return (o0 ^ o1) >> 9;
}

// ------------------- IoU (shared by k1/k2 for bit-identical values) -------------------
__device__ __forceinline__ float iou_one(float a0, float a1, float a2, float a3,
                                         float t0, float t1, float t2, float t3) {
    float xtl = fmaxf(a0, t0), ytl = fmaxf(a1, t1);
    float xrb = fminf(a2, t2), yrb = fminf(a3, t3);
    float iw = fmaxf(xrb - xtl + 1.0f, 0.0f);
    float ih = fmaxf(yrb - ytl + 1.0f, 0.0f);
    float inter = iw * ih;
    float area1 = (a2 - a0 + 1.0f) * (a3 - a1 + 1.0f);
    float area2 = (t2 - t0 + 1.0f) * (t3 - t1 + 1.0f);
    return inter / (area1 + area2 - inter);
}

// ------------------- K0: zero control region, derive per-image keys -------------------
__global__ void k0_init(uint32_t* __restrict__ ws) {
    int t = blockIdx.x * blockDim.x + threadIdx.x;
    for (int j = ZERO_BEG + t; j < ZERO_END; j += gridDim.x * blockDim.x) ws[j] = 0u;
    if (t == 0) {
        for (int b = 0; b < Bn; ++b) {
            uint32_t o0, o1;
            tf2x32(0u, 42u, 0u, (uint32_t)b, o0, o1);
            ws[OFF_KEYS + 2*b] = o0; ws[OFF_KEYS + 2*b + 1] = o1;
        }
    }
}

// ------------------- K1: per-target column max IoU -------------------
// 256 blocks/image (4 waves/SIMD for latency hiding), 2 anchors/thread in regs,
// cm[32] register accumulate, targets via block-uniform (scalar) loads.
#define K1_BLOCKS 256
__global__ void __launch_bounds__(256) k1_colmax(const float* __restrict__ anchors,
                                                 const float* __restrict__ targets,
                                                 uint32_t* __restrict__ ws) {
    int b = blockIdx.y;
    __shared__ float part[4][Mn];
    int i1 = blockIdx.x * 256 + threadIdx.x;
    int i2 = i1 + K1_BLOCKS * 256;
    bool v2 = (i2 < Nn);
    float4 a1 = ((const float4*)anchors)[b * Nn + i1];
    float4 a2 = ((const float4*)anchors)[b * Nn + (v2 ? i2 : i1)];
    float cm[Mn];
    #pragma unroll 8
    for (int t = 0; t < Mn; ++t) {
        float4 tv = ((const float4*)targets)[b * Mn + t];   // uniform -> s_load
        float u1 = iou_one(a1.x, a1.y, a1.z, a1.w, tv.x, tv.y, tv.z, tv.w);
        float u2 = iou_one(a2.x, a2.y, a2.z, a2.w, tv.x, tv.y, tv.z, tv.w);
        cm[t] = fmaxf(u1, v2 ? u2 : 0.0f);
    }
    #pragma unroll
    for (int t = 0; t < Mn; ++t) {
        #pragma unroll
        for (int o = 32; o > 0; o >>= 1) cm[t] = fmaxf(cm[t], __shfl_xor(cm[t], o, 64));
    }
    int wid = threadIdx.x >> 6, lane = threadIdx.x & 63;
    if (lane == 0) {
        #pragma unroll
        for (int t = 0; t < Mn; ++t) part[wid][t] = cm[t];
    }
    __syncthreads();
    if (threadIdx.x < Mn) {
        float v = fmaxf(fmaxf(part[0][threadIdx.x], part[1][threadIdx.x]),
                        fmaxf(part[2][threadIdx.x], part[3][threadIdx.x]));
        atomicMax(&ws[OFF_COLMAX + b * Mn + threadIdx.x], __float_as_uint(v));
    }
}

// ------------------- K2: categorize, RNG, histogram, positive list -------------------
// Targets + colmax + keys read via block-uniform (scalar) loads; no LDS.
// Writes ONE packed word per anchor: m | (cat<<24).
__global__ void __launch_bounds__(256) k2_cat(const float* __restrict__ anchors,
                                              const float* __restrict__ targets,
                                              const float* __restrict__ sizes,
                                              uint32_t* __restrict__ ws) {
    int b = blockIdx.y;
    int i = blockIdx.x * 256 + threadIdx.x;
    float4 av = ((const float4*)anchors)[b * Nn + i];
    float rowmax = -1.0f; int ori = 0; bool restore = false;
    #pragma unroll 8
    for (int t = 0; t < Mn; ++t) {
        float4 tv = ((const float4*)targets)[b * Mn + t];                 // s_load
        float cmf = __uint_as_float(ws[OFF_COLMAX + b * Mn + t]);         // s_load
        float iou = iou_one(av.x, av.y, av.z, av.w, tv.x, tv.y, tv.z, tv.w);
        if (iou > rowmax) { rowmax = iou; ori = t; }
        restore = restore || (iou == cmf);
    }
    float sh = sizes[b * 2 + 0], sw = sizes[b * 2 + 1];
    bool inside = (av.x >= 0.0f) && (av.y >= 0.0f) && (av.z <= sw - 1.0f) && (av.w <= sh - 1.0f);
    uint32_t cat = 0;  // 0 ignore, 1 neg, 2 pos
    if (inside) {
        if (restore || rowmax >= FG_THR) cat = 2;
        else if (rowmax < BG_THR) cat = 1;
    }
    uint32_t k0 = ws[OFF_KEYS + 2 * b], k1 = ws[OFF_KEYS + 2 * b + 1];
    uint32_t m = rng_m23(k0, k1, (uint32_t)i);
    ws[OFF_PACK + b * Nn + i] = m | (cat << 24);
    if (cat == 2u) {
        uint32_t p = atomicAdd(&ws[OFF_POSCNT + b], 1u);
        if (p < POS_CAP) {
            ws[OFF_PLIST + ((uint32_t)b * POS_CAP + p) * 2 + 0] = m;
            ws[OFF_PLIST + ((uint32_t)b * POS_CAP + p) * 2 + 1] = (uint32_t)i | ((uint32_t)ori << 17);
        }
    } else if (cat == 1u) {
        atomicAdd(&ws[OFF_HIST + b * 1024 + (m >> 13)], 1u);
    }
}

// ------------------- K2.5: find boundary bucket per image (parallel scan) -------------------
__global__ void __launch_bounds__(256) k25_bound(uint32_t* __restrict__ ws) {
    int b = blockIdx.x;
    int t = threadIdx.x;
    __shared__ uint32_t csum[256];
    uint32_t h[4];
    uint32_t sum = 0;
    #pragma unroll
    for (int j = 0; j < 4; ++j) { h[j] = ws[OFF_HIST + b * 1024 + 4 * t + j]; sum += h[j]; }
    csum[t] = sum;
    __syncthreads();
    // inclusive suffix sum over 256 chunk sums (Hillis-Steele)
    for (int off = 1; off < 256; off <<= 1) {
        uint32_t mine = csum[t];
        uint32_t add = (t + off < 256) ? csum[t + off] : 0u;
        __syncthreads();
        csum[t] = mine + add;
        __syncthreads();
    }
    uint32_t pc = ws[OFF_POSCNT + b];
    int num_pos = (pc < (uint32_t)NPOSMAX) ? (int)pc : NPOSMAX;
    int k_neg = NPERIM - num_pos;
    uint32_t total = csum[0];
    if ((int)total < k_neg) {
        if (t == 0) {
            ws[OFF_BOUND + b] = 0xFFFFFFFFu;   // -1
            ws[OFF_NEED + b] = 0u;
            atomicAdd(&ws[OFF_COUNT], (uint32_t)(num_pos + (int)total));
        }
        return;
    }
    // exactly one thread owns the crossing chunk
    uint32_t incl = csum[t];
    uint32_t next = (t < 255) ? csum[t + 1] : 0u;   // suffix sum excluding my chunk
    if ((int)incl >= k_neg && (int)next < k_neg) {
        int cum = (int)next;   // buckets strictly above my chunk
        int boundary = -1, needed = 0;
        #pragma unroll
        for (int j = 3; j >= 0; --j) {
            int c = (int)h[j];
            if (cum + c >= k_neg) { boundary = 4 * t + j; needed = k_neg - cum; break; }
            cum += c;
        }
        ws[OFF_BOUND + b] = (uint32_t)boundary;
        ws[OFF_NEED + b] = (uint32_t)needed;
        atomicAdd(&ws[OFF_COUNT], (uint32_t)(num_pos + k_neg));
    }
}

// ------------------- K3: BCE sum for clearly-selected negatives; gather boundary -------------------
__global__ void __launch_bounds__(256) k3_neg(const float* __restrict__ logits,
                                              uint32_t* __restrict__ ws) {
    int b = blockIdx.y;
    int i = blockIdx.x * 256 + threadIdx.x;
    int bd = (int)(int32_t)ws[OFF_BOUND + b];    // uniform -> s_load
    uint32_t p = ws[OFF_PACK + b * Nn + i];
    uint32_t cat = p >> 24;
    float local = 0.0f;
    if (cat == 1u) {
        uint32_t m = p & 0x7FFFFFu;
        int bk = (int)(m >> 13);
        if (bk > bd) {
            int a = i % An, hw = i / An;
            float l = logits[(b * An + a) * HWn + hw];
            local = fmaxf(l, 0.0f) + log1pf(expf(-fabsf(l)));   // BCE(l, 0)
        } else if (bk == bd) {
            uint32_t q = atomicAdd(&ws[OFF_BNDCNT + b], 1u);
            if (q < BND_CAP) {
                ws[OFF_BLIST + ((uint32_t)b * BND_CAP + q) * 2 + 0] = m;
                ws[OFF_BLIST + ((uint32_t)b * BND_CAP + q) * 2 + 1] = (uint32_t)i;
            }
        }
    }
    __shared__ float red[256];
    red[threadIdx.x] = local;
    __syncthreads();
    for (int s = 128; s > 0; s >>= 1) {
        if ((int)threadIdx.x < s) red[threadIdx.x] += red[threadIdx.x + s];
        __syncthreads();
    }
    if (threadIdx.x == 0 && red[0] != 0.0f) atomicAdd((float*)&ws[OFF_CLS], red[0]);
}

// ------------------- K4: per-image finalize + final divide (merged k5) -------------------
__device__ __forceinline__ bool sel_less(uint2 a, uint2 b) {
    // selection order: larger priority m first; tie -> smaller index first (JAX top_k)
    return (a.x > b.x) || (a.x == b.x && a.y < b.y);
}

__device__ void bitonic_sort_shared(uint2* buf, int n) {   // n = pow2
    for (int k = 2; k <= n; k <<= 1) {
        for (int j = k >> 1; j > 0; j >>= 1) {
            for (int t = (int)threadIdx.x; t < n; t += 256) {
                int ixj = t ^ j;
                if (ixj > t) {
                    uint2 x = buf[t], y = buf[ixj];
                    bool up = ((t & k) == 0);
                    bool sw = up ? sel_less(y, x) : sel_less(x, y);
                    if (sw) { buf[t] = y; buf[ixj] = x; }
                }
            }
            __syncthreads();
        }
    }
}

__global__ void __launch_bounds__(256) k4_final(const float* __restrict__ anchors,
                                                const float* __restrict__ targets,
                                                const float* __restrict__ logits,
                                                const float* __restrict__ bregs,
                                                uint32_t* __restrict__ ws,
                                                float* __restrict__ out) {
    int b = blockIdx.x;
    __shared__ uint2 buf[BND_CAP];
    __shared__ float red[256];
    float cls = 0.0f, reg = 0.0f;

    // ----- positives -----
    uint32_t pcu = ws[OFF_POSCNT + b];
    int pc = (pcu < (uint32_t)POS_CAP) ? (int)pcu : POS_CAP;
    const uint32_t* plist = ws + OFF_PLIST + (size_t)b * POS_CAP * 2;
    int psel = (pc < NPOSMAX) ? pc : NPOSMAX;
    bool use_buf = false;
    if (pc > NPOSMAX) {
        int n = (pc < BND_CAP) ? pc : BND_CAP;
        for (int j = (int)threadIdx.x; j < n; j += 256) buf[j] = make_uint2(plist[2*j], plist[2*j+1]);
        int npad = 1; while (npad < n) npad <<= 1;
        for (int j = (int)threadIdx.x; j < npad; j += 256) if (j >= n) buf[j] = make_uint2(0u, 0xFFFFFFFFu);
        __syncthreads();
        bitonic_sort_shared(buf, npad);
        use_buf = true;
        psel = (NPOSMAX < n) ? NPOSMAX : n;
    }
    for (int j = (int)threadIdx.x; j < psel; j += 256) {
        uint32_t packed = use_buf ? buf[j].y : plist[2*j+1];
        int i = (int)(packed & 0x1FFFFu);
        int ori = (int)(packed >> 17);
        int a = i % An, hw = i / An;
        float l = logits[(b * An + a) * HWn + hw];
        cls += fmaxf(l, 0.0f) - l + log1pf(expf(-fabsf(l)));   // BCE(l, 1)
        float4 av = ((const float4*)anchors)[b * Nn + i];
        float4 tv = ((const float4*)targets)[b * Mn + ori];
        float aws = av.z - av.x + 1.0f, ahs = av.w - av.y + 1.0f;
        float axc = av.x + 0.5f * aws, ayc = av.y + 0.5f * ahs;
        float tws = tv.z - tv.x + 1.0f, ths = tv.w - tv.y + 1.0f;
        float txc = tv.x + 0.5f * tws, tyc = tv.y + 0.5f * ths;
        float off0 = (txc - axc) / aws;
        float off1 = (tyc - ayc) / ahs;
        float off2 = logf(tws / aws);
        float off3 = logf(ths / ahs);
        float br0 = bregs[(b * 12 + a * 4 + 0) * HWn + hw];
        float br1 = bregs[(b * 12 + a * 4 + 1) * HWn + hw];
        float br2 = bregs[(b * 12 + a * 4 + 2) * HWn + hw];
        float br3 = bregs[(b * 12 + a * 4 + 3) * HWn + hw];
        float d;
        d = fabsf(br0 - off0); reg += (d < BETA) ? 0.5f * d * d / BETA : d - 0.5f * BETA;
        d = fabsf(br1 - off1); reg += (d < BETA) ? 0.5f * d * d / BETA : d - 0.5f * BETA;
        d = fabsf(br2 - off2); reg += (d < BETA) ? 0.5f * d * d / BETA : d - 0.5f * BETA;
        d = fabsf(br3 - off3); reg += (d < BETA) ? 0.5f * d * d / BETA : d - 0.5f * BETA;
    }
    __syncthreads();

    // ----- boundary-bucket negatives -----
    int need = (int)ws[OFF_NEED + b];
    if (need > 0) {
        uint32_t nbu = ws[OFF_BNDCNT + b];
        int nb = (nbu < (uint32_t)BND_CAP) ? (int)nbu : BND_CAP;
        const uint32_t* blist = ws + OFF_BLIST + (size_t)b * BND_CAP * 2;
        for (int j = (int)threadIdx.x; j < nb; j += 256) buf[j] = make_uint2(blist[2*j], blist[2*j+1]);
        int npad = 1; while (npad < nb) npad <<= 1;
        for (int j = (int)threadIdx.x; j < npad; j += 256) if (j >= nb) buf[j] = make_uint2(0u, 0xFFFFFFFFu);
        __syncthreads();
        bitonic_sort_shared(buf, npad);
        int sel = (need < nb) ? need : nb;
        for (int j = (int)threadIdx.x; j < sel; j += 256) {
            int i = (int)buf[j].y;
            int a = i % An, hw = i / An;
            float l = logits[(b * An + a) * HWn + hw];
            cls += fmaxf(l, 0.0f) + log1pf(expf(-fabsf(l)));   // BCE(l, 0)
        }
    }

    // ----- block reductions -----
    red[threadIdx.x] = cls;
    __syncthreads();
    for (int s = 128; s > 0; s >>= 1) {
        if ((int)threadIdx.x < s) red[threadIdx.x] += red[threadIdx.x + s];
        __syncthreads();
    }
    if (threadIdx.x == 0 && red[0] != 0.0f) atomicAdd((float*)&ws[OFF_CLS], red[0]);
    __syncthreads();
    red[threadIdx.x] = reg;
    __syncthreads();
    for (int s = 128; s > 0; s >>= 1) {
        if ((int)threadIdx.x < s) red[threadIdx.x] += red[threadIdx.x + s];
        __syncthreads();
    }
    if (threadIdx.x == 0) {
        if (red[0] != 0.0f) atomicAdd((float*)&ws[OFF_REG], red[0]);
        __threadfence();
        uint32_t old = atomicAdd(&ws[OFF_DONE], 1u);
        if (old == Bn - 1) {   // last block: all sums visible -> final divide
            float cls_tot = __uint_as_float(atomicAdd(&ws[OFF_CLS], 0u));
            float reg_tot = __uint_as_float(atomicAdd(&ws[OFF_REG], 0u));
            float cnt = (float)atomicAdd(&ws[OFF_COUNT], 0u);
            out[0] = cls_tot / cnt;
            out[1] = reg_tot / cnt;
        }
    }
}

extern "C" void kernel_launch(void* const* d_in, const int* in_sizes, int n_in,
                              void* d_out, int out_size, void* d_ws, size_t ws_size,
                              hipStream_t stream) {
    const float* anchors = (const float*)d_in[0];   // [B, N, 4]
    const float* logits  = (const float*)d_in[1];   // [B, A, H, W]
    const float* bregs   = (const float*)d_in[2];   // [B, 4A, H, W]
    const float* sizes   = (const float*)d_in[3];   // [B, 2]
    const float* targets = (const float*)d_in[4];   // [B, M, 4]
    float* out = (float*)d_out;
    uint32_t* ws = (uint32_t*)d_ws;

    dim3 gridN(Nn / 256, Bn);
    k0_init<<<dim3(64), dim3(256), 0, stream>>>(ws);
    k1_colmax<<<dim3(K1_BLOCKS, Bn), dim3(256), 0, stream>>>(anchors, targets, ws);
    k2_cat<<<gridN, dim3(256), 0, stream>>>(anchors, targets, sizes, ws);
    k25_bound<<<dim3(Bn), dim3(256), 0, stream>>>(ws);
    k3_neg<<<gridN, dim3(256), 0, stream>>>(logits, ws);
    k4_final<<<dim3(Bn), dim3(256), 0, stream>>>(anchors, targets, logits, bregs, ws, out);
}

// Round 4
// 168.886 us; speedup vs baseline: 6.2563x; 1.0524x over previous
//
#include <hip/hip_runtime.h>
#include <stdint.h>

#define Bn 4
#define An 3
#define Hn 168
#define Wn 256
#define Mn 32
#define HWn (Hn*Wn)
#define Nn (HWn*An)          // 129024
#define POS_CAP 8192
#define BND_CAP 2048
#define NPERIM 256
#define NPOSMAX 128
#define FG_THR 0.7f
#define BG_THR 0.3f
#define BETA (1.0f/9.0f)

// ---- workspace layout (uint32 word offsets) ----
#define OFF_KEYS   0            // Bn*2 (written in k0, outside zero range)
#define OFF_COLMAX 8            // Bn*Mn = 128 (float bits, atomicMax)
#define OFF_POSCNT 136          // Bn
#define OFF_BNDCNT 140          // Bn
#define OFF_BOUND  144          // Bn (int32, -1 = all negatives selected)
#define OFF_NEED   148          // Bn
#define OFF_COUNT  152          // 1 (uint)
#define OFF_CLS    153          // 1 (float bits)
#define OFF_REG    154          // 1 (float bits)
#define OFF_DONE   155          // 1 (uint, k4 completion counter)
#define OFF_HIST   160          // Bn*1024 = 4096 -> end 4256
#define ZERO_BEG   8
#define ZERO_END   4256
#define OFF_PACK   4256         // Bn*Nn  (m | cat<<24)   -> 520352
#define OFF_PLIST  520352       // Bn*POS_CAP*2           -> 585888
#define OFF_BLIST  585888       // Bn*BND_CAP*2           -> 602272

// ------------------- threefry2x32 (20 rounds) -------------------
__device__ __forceinline__ uint32_t rotl32(uint32_t v, int n) { return (v << n) | (v >> (32 - n)); }

__device__ __forceinline__ void tf2x32(uint32_t k0, uint32_t k1, uint32_t x0, uint32_t x1,
                                       uint32_t& o0, uint32_t& o1) {
    uint32_t k2 = k0 ^ k1 ^ 0x1BD11BDAu;
    x0 += k0; x1 += k1;
    x0 += x1; x1 = rotl32(x1, 13); x1 ^= x0;
    x0 += x1; x1 = rotl32(x1, 15); x1 ^= x0;
    x0 += x1; x1 = rotl32(x1, 26); x1 ^= x0;
    x0 += x1; x1 = rotl32(x1, 6);  x1 ^= x0;
    x0 += k1; x1 += k2 + 1u;
    x0 += x1; x1 = rotl32(x1, 17); x1 ^= x0;
    x0 += x1; x1 = rotl32(x1, 29); x1 ^= x0;
    x0 += x1; x1 = rotl32(x1, 16); x1 ^= x0;
    x0 += x1; x1 = rotl32(x1, 24); x1 ^= x0;
    x0 += k2; x1 += k0 + 2u;
    x0 += x1; x1 = rotl32(x1, 13); x1 ^= x0;
    x0 += x1; x1 = rotl32(x1, 15); x1 ^= x0;
    x0 += x1; x1 = rotl32(x1, 26); x1 ^= x0;
    x0 += x1; x1 = rotl32(x1, 6);  x1 ^= x0;
    x0 += k0; x1 += k1 + 3u;
    x0 += x1; x1 = rotl32(x1, 17); x1 ^= x0;
    x0 += x1; x1 = rotl32(x1, 29); x1 ^= x0;
    x0 += x1; x1 = rotl32(x1, 16); x1 ^= x0;
    x0 += x1; x1 = rotl32(x1, 24); x1 ^= x0;
    x0 += k1; x1 += k2 + 4u;
    x0 += x1; x1 = rotl32(x1, 13); x1 ^= x0;
    x0 += x1; x1 = rotl32(x1, 15); x1 ^= x0;
    x0 += x1; x1 = rotl32(x1, 26); x1 ^= x0;
    x0 += x1; x1 = rotl32(x1, 6);  x1 ^= x0;
    x0 += k2; x1 += k0 + 5u;
    o0 = x0; o1 = x1;
}

__device__ __forceinline__ uint32_t rng_m23(uint32_t k0, uint32_t k1, uint32_t i) {
    uint32_t o0, o1;
    tf2x32(k0, k1, 0u, i, o0, o1);
    return (o0 ^ o1) >> 9;
}

// ------------------- IoU (shared by k1/k2 for bit-identical values) -------------------
// v_rcp_f32 (~1 ulp) instead of the ~10-inst exact-div sequence. Both k1 and k2
// use this same function, so the 'iou == colmax' restore equality is preserved
// exactly; only measure-zero 0.3/0.7 threshold crossings can differ from XLA.
__device__ __forceinline__ float iou_one(float a0, float a1, float a2, float a3,
                                         float t0, float t1, float t2, float t3) {
    float xtl = fmaxf(a0, t0), ytl = fmaxf(a1, t1);
    float xrb = fminf(a2, t2), yrb = fminf(a3, t3);
    float iw = fmaxf(xrb - xtl + 1.0f, 0.0f);
    float ih = fmaxf(yrb - ytl + 1.0f, 0.0f);
    float inter = iw * ih;
    float area1 = (a2 - a0 + 1.0f) * (a3 - a1 + 1.0f);
    float area2 = (t2 - t0 + 1.0f) * (t3 - t1 + 1.0f);
    return inter * __builtin_amdgcn_rcpf(area1 + area2 - inter);
}

// ------------------- K0: zero control region, derive per-image keys -------------------
__global__ void k0_init(uint32_t* __restrict__ ws) {
    int t = blockIdx.x * blockDim.x + threadIdx.x;
    for (int j = ZERO_BEG + t; j < ZERO_END; j += gridDim.x * blockDim.x) ws[j] = 0u;
    if (t == 0) {
        for (int b = 0; b < Bn; ++b) {
            uint32_t o0, o1;
            tf2x32(0u, 42u, 0u, (uint32_t)b, o0, o1);
            ws[OFF_KEYS + 2*b] = o0; ws[OFF_KEYS + 2*b + 1] = o1;
        }
    }
}

// ------------------- K1: per-target column max IoU -------------------
// 8 anchors/thread (ILP + amortized reduction), 63 blocks/image, no tail.
#define K1_APT 8
#define K1_BLOCKS 63
#define K1_STRIDE (K1_BLOCKS * 256)    // 16128
__global__ void __launch_bounds__(256) k1_colmax(const float* __restrict__ anchors,
                                                 const float* __restrict__ targets,
                                                 uint32_t* __restrict__ ws) {
    int b = blockIdx.y;
    __shared__ float part[4][Mn];
    int base = blockIdx.x * 256 + threadIdx.x;
    float4 a[K1_APT];
    #pragma unroll
    for (int k = 0; k < K1_APT; ++k)
        a[k] = ((const float4*)anchors)[b * Nn + base + k * K1_STRIDE];
    float cm[Mn];
    #pragma unroll 4
    for (int t = 0; t < Mn; ++t) {
        float4 tv = ((const float4*)targets)[b * Mn + t];
        float m0 = 0.0f;
        #pragma unroll
        for (int k = 0; k < K1_APT; ++k)
            m0 = fmaxf(m0, iou_one(a[k].x, a[k].y, a[k].z, a[k].w, tv.x, tv.y, tv.z, tv.w));
        cm[t] = m0;
    }
    #pragma unroll
    for (int t = 0; t < Mn; ++t) {
        #pragma unroll
        for (int o = 32; o > 0; o >>= 1) cm[t] = fmaxf(cm[t], __shfl_xor(cm[t], o, 64));
    }
    int wid = threadIdx.x >> 6, lane = threadIdx.x & 63;
    if (lane == 0) {
        #pragma unroll
        for (int t = 0; t < Mn; ++t) part[wid][t] = cm[t];
    }
    __syncthreads();
    if (threadIdx.x < Mn) {
        float v = fmaxf(fmaxf(part[0][threadIdx.x], part[1][threadIdx.x]),
                        fmaxf(part[2][threadIdx.x], part[3][threadIdx.x]));
        atomicMax(&ws[OFF_COLMAX + b * Mn + threadIdx.x], __float_as_uint(v));
    }
}

// ------------------- K2: categorize, RNG, histogram, positive list -------------------
// 4 anchors/thread, 126 blocks/image; target loads amortized 4x, 4 independent
// threefry chains for ILP.
#define K2_APT 4
#define K2_BLOCKS 126
#define K2_STRIDE (K2_BLOCKS * 256)    // 32256
__global__ void __launch_bounds__(256) k2_cat(const float* __restrict__ anchors,
                                              const float* __restrict__ targets,
                                              const float* __restrict__ sizes,
                                              uint32_t* __restrict__ ws) {
    int b = blockIdx.y;
    int base = blockIdx.x * 256 + threadIdx.x;
    float4 av[K2_APT];
    #pragma unroll
    for (int k = 0; k < K2_APT; ++k)
        av[k] = ((const float4*)anchors)[b * Nn + base + k * K2_STRIDE];
    float rowmax[K2_APT]; int ori[K2_APT]; bool restore[K2_APT];
    #pragma unroll
    for (int k = 0; k < K2_APT; ++k) { rowmax[k] = -1.0f; ori[k] = 0; restore[k] = false; }
    #pragma unroll 4
    for (int t = 0; t < Mn; ++t) {
        float4 tv = ((const float4*)targets)[b * Mn + t];
        float cmf = __uint_as_float(ws[OFF_COLMAX + b * Mn + t]);
        #pragma unroll
        for (int k = 0; k < K2_APT; ++k) {
            float iou = iou_one(av[k].x, av[k].y, av[k].z, av[k].w, tv.x, tv.y, tv.z, tv.w);
            if (iou > rowmax[k]) { rowmax[k] = iou; ori[k] = t; }
            restore[k] = restore[k] || (iou == cmf);
        }
    }
    float sh = sizes[b * 2 + 0], sw = sizes[b * 2 + 1];
    uint32_t key0 = ws[OFF_KEYS + 2 * b], key1 = ws[OFF_KEYS + 2 * b + 1];
    #pragma unroll
    for (int k = 0; k < K2_APT; ++k) {
        int i = base + k * K2_STRIDE;
        bool inside = (av[k].x >= 0.0f) && (av[k].y >= 0.0f) &&
                      (av[k].z <= sw - 1.0f) && (av[k].w <= sh - 1.0f);
        uint32_t cat = 0;  // 0 ignore, 1 neg, 2 pos
        if (inside) {
            if (restore[k] || rowmax[k] >= FG_THR) cat = 2;
            else if (rowmax[k] < BG_THR) cat = 1;
        }
        uint32_t m = rng_m23(key0, key1, (uint32_t)i);
        ws[OFF_PACK + b * Nn + i] = m | (cat << 24);
        if (cat == 2u) {
            uint32_t p = atomicAdd(&ws[OFF_POSCNT + b], 1u);
            if (p < POS_CAP) {
                ws[OFF_PLIST + ((uint32_t)b * POS_CAP + p) * 2 + 0] = m;
                ws[OFF_PLIST + ((uint32_t)b * POS_CAP + p) * 2 + 1] = (uint32_t)i | ((uint32_t)ori[k] << 17);
            }
        } else if (cat == 1u) {
            atomicAdd(&ws[OFF_HIST + b * 1024 + (m >> 13)], 1u);
        }
    }
}

// ------------------- K2.5: find boundary bucket per image (parallel scan) -------------------
__global__ void __launch_bounds__(256) k25_bound(uint32_t* __restrict__ ws) {
    int b = blockIdx.x;
    int t = threadIdx.x;
    __shared__ uint32_t csum[256];
    uint32_t h[4];
    uint32_t sum = 0;
    #pragma unroll
    for (int j = 0; j < 4; ++j) { h[j] = ws[OFF_HIST + b * 1024 + 4 * t + j]; sum += h[j]; }
    csum[t] = sum;
    __syncthreads();
    for (int off = 1; off < 256; off <<= 1) {
        uint32_t mine = csum[t];
        uint32_t add = (t + off < 256) ? csum[t + off] : 0u;
        __syncthreads();
        csum[t] = mine + add;
        __syncthreads();
    }
    uint32_t pc = ws[OFF_POSCNT + b];
    int num_pos = (pc < (uint32_t)NPOSMAX) ? (int)pc : NPOSMAX;
    int k_neg = NPERIM - num_pos;
    uint32_t total = csum[0];
    if ((int)total < k_neg) {
        if (t == 0) {
            ws[OFF_BOUND + b] = 0xFFFFFFFFu;
            ws[OFF_NEED + b] = 0u;
            atomicAdd(&ws[OFF_COUNT], (uint32_t)(num_pos + (int)total));
        }
        return;
    }
    uint32_t incl = csum[t];
    uint32_t next = (t < 255) ? csum[t + 1] : 0u;
    if ((int)incl >= k_neg && (int)next < k_neg) {
        int cum = (int)next;
        int boundary = -1, needed = 0;
        #pragma unroll
        for (int j = 3; j >= 0; --j) {
            int c = (int)h[j];
            if (cum + c >= k_neg) { boundary = 4 * t + j; needed = k_neg - cum; break; }
            cum += c;
        }
        ws[OFF_BOUND + b] = (uint32_t)boundary;
        ws[OFF_NEED + b] = (uint32_t)needed;
        atomicAdd(&ws[OFF_COUNT], (uint32_t)(num_pos + k_neg));
    }
}

// ------------------- K3: BCE sum for clearly-selected negatives; gather boundary -------------------
__global__ void __launch_bounds__(256) k3_neg(const float* __restrict__ logits,
                                              uint32_t* __restrict__ ws) {
    int b = blockIdx.y;
    int i = blockIdx.x * 256 + threadIdx.x;
    int bd = (int)(int32_t)ws[OFF_BOUND + b];
    uint32_t p = ws[OFF_PACK + b * Nn + i];
    uint32_t cat = p >> 24;
    float local = 0.0f;
    if (cat == 1u) {
        uint32_t m = p & 0x7FFFFFu;
        int bk = (int)(m >> 13);
        if (bk > bd) {
            int a = i % An, hw = i / An;
            float l = logits[(b * An + a) * HWn + hw];
            local = fmaxf(l, 0.0f) + log1pf(expf(-fabsf(l)));   // BCE(l, 0)
        } else if (bk == bd) {
            uint32_t q = atomicAdd(&ws[OFF_BNDCNT + b], 1u);
            if (q < BND_CAP) {
                ws[OFF_BLIST + ((uint32_t)b * BND_CAP + q) * 2 + 0] = m;
                ws[OFF_BLIST + ((uint32_t)b * BND_CAP + q) * 2 + 1] = (uint32_t)i;
            }
        }
    }
    __shared__ float red[256];
    red[threadIdx.x] = local;
    __syncthreads();
    for (int s = 128; s > 0; s >>= 1) {
        if ((int)threadIdx.x < s) red[threadIdx.x] += red[threadIdx.x + s];
        __syncthreads();
    }
    if (threadIdx.x == 0 && red[0] != 0.0f) atomicAdd((float*)&ws[OFF_CLS], red[0]);
}

// ------------------- K4: per-image finalize + final divide -------------------
__device__ __forceinline__ bool sel_less(uint2 a, uint2 b) {
    return (a.x > b.x) || (a.x == b.x && a.y < b.y);
}

__device__ void bitonic_sort_shared(uint2* buf, int n) {   // n = pow2
    for (int k = 2; k <= n; k <<= 1) {
        for (int j = k >> 1; j > 0; j >>= 1) {
            for (int t = (int)threadIdx.x; t < n; t += 256) {
                int ixj = t ^ j;
                if (ixj > t) {
                    uint2 x = buf[t], y = buf[ixj];
                    bool up = ((t & k) == 0);
                    bool sw = up ? sel_less(y, x) : sel_less(x, y);
                    if (sw) { buf[t] = y; buf[ixj] = x; }
                }
            }
            __syncthreads();
        }
    }
}

__global__ void __launch_bounds__(256) k4_final(const float* __restrict__ anchors,
                                                const float* __restrict__ targets,
                                                const float* __restrict__ logits,
                                                const float* __restrict__ bregs,
                                                uint32_t* __restrict__ ws,
                                                float* __restrict__ out) {
    int b = blockIdx.x;
    __shared__ uint2 buf[BND_CAP];
    __shared__ float red[256];
    float cls = 0.0f, reg = 0.0f;

    // ----- positives -----
    uint32_t pcu = ws[OFF_POSCNT + b];
    int pc = (pcu < (uint32_t)POS_CAP) ? (int)pcu : POS_CAP;
    const uint32_t* plist = ws + OFF_PLIST + (size_t)b * POS_CAP * 2;
    int psel = (pc < NPOSMAX) ? pc : NPOSMAX;
    bool use_buf = false;
    if (pc > NPOSMAX) {
        int n = (pc < BND_CAP) ? pc : BND_CAP;
        for (int j = (int)threadIdx.x; j < n; j += 256) buf[j] = make_uint2(plist[2*j], plist[2*j+1]);
        int npad = 1; while (npad < n) npad <<= 1;
        for (int j = (int)threadIdx.x; j < npad; j += 256) if (j >= n) buf[j] = make_uint2(0u, 0xFFFFFFFFu);
        __syncthreads();
        bitonic_sort_shared(buf, npad);
        use_buf = true;
        psel = (NPOSMAX < n) ? NPOSMAX : n;
    }
    for (int j = (int)threadIdx.x; j < psel; j += 256) {
        uint32_t packed = use_buf ? buf[j].y : plist[2*j+1];
        int i = (int)(packed & 0x1FFFFu);
        int ori = (int)(packed >> 17);
        int a = i % An, hw = i / An;
        float l = logits[(b * An + a) * HWn + hw];
        cls += fmaxf(l, 0.0f) - l + log1pf(expf(-fabsf(l)));   // BCE(l, 1)
        float4 av = ((const float4*)anchors)[b * Nn + i];
        float4 tv = ((const float4*)targets)[b * Mn + ori];
        float aws = av.z - av.x + 1.0f, ahs = av.w - av.y + 1.0f;
        float axc = av.x + 0.5f * aws, ayc = av.y + 0.5f * ahs;
        float tws = tv.z - tv.x + 1.0f, ths = tv.w - tv.y + 1.0f;
        float txc = tv.x + 0.5f * tws, tyc = tv.y + 0.5f * ths;
        float off0 = (txc - axc) / aws;
        float off1 = (tyc - ayc) / ahs;
        float off2 = logf(tws / aws);
        float off3 = logf(ths / ahs);
        float br0 = bregs[(b * 12 + a * 4 + 0) * HWn + hw];
        float br1 = bregs[(b * 12 + a * 4 + 1) * HWn + hw];
        float br2 = bregs[(b * 12 + a * 4 + 2) * HWn + hw];
        float br3 = bregs[(b * 12 + a * 4 + 3) * HWn + hw];
        float d;
        d = fabsf(br0 - off0); reg += (d < BETA) ? 0.5f * d * d / BETA : d - 0.5f * BETA;
        d = fabsf(br1 - off1); reg += (d < BETA) ? 0.5f * d * d / BETA : d - 0.5f * BETA;
        d = fabsf(br2 - off2); reg += (d < BETA) ? 0.5f * d * d / BETA : d - 0.5f * BETA;
        d = fabsf(br3 - off3); reg += (d < BETA) ? 0.5f * d * d / BETA : d - 0.5f * BETA;
    }
    __syncthreads();

    // ----- boundary-bucket negatives -----
    int need = (int)ws[OFF_NEED + b];
    if (need > 0) {
        uint32_t nbu = ws[OFF_BNDCNT + b];
        int nb = (nbu < (uint32_t)BND_CAP) ? (int)nbu : BND_CAP;
        const uint32_t* blist = ws + OFF_BLIST + (size_t)b * BND_CAP * 2;
        for (int j = (int)threadIdx.x; j < nb; j += 256) buf[j] = make_uint2(blist[2*j], blist[2*j+1]);
        int npad = 1; while (npad < nb) npad <<= 1;
        for (int j = (int)threadIdx.x; j < npad; j += 256) if (j >= nb) buf[j] = make_uint2(0u, 0xFFFFFFFFu);
        __syncthreads();
        bitonic_sort_shared(buf, npad);
        int sel = (need < nb) ? need : nb;
        for (int j = (int)threadIdx.x; j < sel; j += 256) {
            int i = (int)buf[j].y;
            int a = i % An, hw = i / An;
            float l = logits[(b * An + a) * HWn + hw];
            cls += fmaxf(l, 0.0f) + log1pf(expf(-fabsf(l)));   // BCE(l, 0)
        }
    }

    // ----- block reductions -----
    red[threadIdx.x] = cls;
    __syncthreads();
    for (int s = 128; s > 0; s >>= 1) {
        if ((int)threadIdx.x < s) red[threadIdx.x] += red[threadIdx.x + s];
        __syncthreads();
    }
    if (threadIdx.x == 0 && red[0] != 0.0f) atomicAdd((float*)&ws[OFF_CLS], red[0]);
    __syncthreads();
    red[threadIdx.x] = reg;
    __syncthreads();
    for (int s = 128; s > 0; s >>= 1) {
        if ((int)threadIdx.x < s) red[threadIdx.x] += red[threadIdx.x + s];
        __syncthreads();
    }
    if (threadIdx.x == 0) {
        if (red[0] != 0.0f) atomicAdd((float*)&ws[OFF_REG], red[0]);
        __threadfence();
        uint32_t old = atomicAdd(&ws[OFF_DONE], 1u);
        if (old == Bn - 1) {
            float cls_tot = __uint_as_float(atomicAdd(&ws[OFF_CLS], 0u));
            float reg_tot = __uint_as_float(atomicAdd(&ws[OFF_REG], 0u));
            float cnt = (float)atomicAdd(&ws[OFF_COUNT], 0u);
            out[0] = cls_tot / cnt;
            out[1] = reg_tot / cnt;
        }
    }
}

extern "C" void kernel_launch(void* const* d_in, const int* in_sizes, int n_in,
                              void* d_out, int out_size, void* d_ws, size_t ws_size,
                              hipStream_t stream) {
    const float* anchors = (const float*)d_in[0];   // [B, N, 4]
    const float* logits  = (const float*)d_in[1];   // [B, A, H, W]
    const float* bregs   = (const float*)d_in[2];   // [B, 4A, H, W]
    const float* sizes   = (const float*)d_in[3];   // [B, 2]
    const float* targets = (const float*)d_in[4];   // [B, M, 4]
    float* out = (float*)d_out;
    uint32_t* ws = (uint32_t*)d_ws;

    k0_init<<<dim3(64), dim3(256), 0, stream>>>(ws);
    k1_colmax<<<dim3(K1_BLOCKS, Bn), dim3(256), 0, stream>>>(anchors, targets, ws);
    k2_cat<<<dim3(K2_BLOCKS, Bn), dim3(256), 0, stream>>>(anchors, targets, sizes, ws);
    k25_bound<<<dim3(Bn), dim3(256), 0, stream>>>(ws);
    k3_neg<<<dim3(Nn / 256, Bn), dim3(256), 0, stream>>>(logits, ws);
    k4_final<<<dim3(Bn), dim3(256), 0, stream>>>(anchors, targets, logits, bregs, ws, out);
}